// Round 4
// baseline (223.587 us; speedup 1.0000x reference)
//
#include <hip/hip_runtime.h>

#define BB 8192
#define KCNT 50

typedef __attribute__((ext_vector_type(8))) short bf16x8;
typedef __attribute__((ext_vector_type(4))) float f32x4;

__device__ __forceinline__ ushort f2bf(float f) {
    union { float f; unsigned u; } v; v.f = f;
    unsigned r = v.u + 0x7FFFu + ((v.u >> 16) & 1u);
    return (ushort)(r >> 16);
}
__device__ __forceinline__ float bf2f(ushort h) {
    union { unsigned u; float f; } v; v.u = ((unsigned)h) << 16;
    return v.f;
}

// ---- prep: all 6 weights [K][N] fp32 -> [N][K] bf16 ----
__global__ __launch_bounds__(256) void prep_weights(
    const float* __restrict__ s0, ushort* __restrict__ d0,   // Wkg 64x64
    const float* __restrict__ s1, ushort* __restrict__ d1,   // W1a 512x128
    const float* __restrict__ s2, ushort* __restrict__ d2,   // W1b 128x512
    const float* __restrict__ s3, ushort* __restrict__ d3,   // W1c 512x128
    const float* __restrict__ s4, ushort* __restrict__ d4,   // W1d 128x64
    const float* __restrict__ s5, ushort* __restrict__ d5)   // W2 64x1024
{
    int gid = blockIdx.x * 256 + threadIdx.x;
    const float* s; ushort* d; int K, N, base;
    if      (gid < 4096)   { s = s0; d = d0; K = 64;  N = 64;   base = 0; }
    else if (gid < 69632)  { s = s1; d = d1; K = 512; N = 128;  base = 4096; }
    else if (gid < 135168) { s = s2; d = d2; K = 128; N = 512;  base = 69632; }
    else if (gid < 200704) { s = s3; d = d3; K = 512; N = 128;  base = 135168; }
    else if (gid < 208896) { s = s4; d = d4; K = 128; N = 64;   base = 200704; }
    else if (gid < 274432) { s = s5; d = d5; K = 64;  N = 1024; base = 208896; }
    else return;
    int e = gid - base;          // e = k*N + n  (coalesced read)
    int k = e / N, n = e % N;
    d[n * K + k] = f2bf(s[e]);
}

// ---- knowledge branch: mask-compacted gather + bf16 MFMA ----
// 1 wave per batch, 4 batches/block. Only mask=1 rows are gathered (~25/50).
__global__ __launch_bounds__(256) void knowledge_bf16(
    const float* __restrict__ kg, const int* __restrict__ idx,
    const int* __restrict__ mask, const ushort* __restrict__ Wkgt,
    const float* __restrict__ bkg, ushort* __restrict__ know)
{
    __shared__ ushort As[4][64 * 72];
    __shared__ ushort Ws[64 * 72];
    __shared__ int    sidx[4][64];

    const int t    = threadIdx.x;
    const int w    = t >> 6;
    const int lane = t & 63;
    const int ln   = lane & 15;
    const int quad = lane >> 4;
    const int b    = blockIdx.x * 4 + w;

    int cnt;
    {
        int id = 0, mk = 0;
        if (lane < KCNT) {
            id = idx[(size_t)b * KCNT + lane];
            mk = mask[(size_t)b * KCNT + lane];
        }
        unsigned long long bal = __ballot(mk != 0);
        cnt = __popcll(bal);
        if (mk) {
            int pos = __popcll(bal & ((1ull << lane) - 1ull));
            sidx[w][pos] = id;
        }
    }
    // stage Wkgt (shared by all 4 waves)
    #pragma unroll
    for (int i = 0; i < 2; ++i) {
        int gid = i * 256 + t;
        int row = gid >> 3, seg = gid & 7;
        *(uint4*)&Ws[row * 72 + seg * 8] = ((const uint4*)(Wkgt + row * 64))[seg];
    }
    __syncthreads();

    // compacted gather, fully unrolled (all loads in flight)
    #pragma unroll
    for (int p = 0; p < 16; ++p) {
        const int row = p * 4 + quad;
        ushort4 o; o.x = 0; o.y = 0; o.z = 0; o.w = 0;
        if (row < cnt) {
            const float4 v = *(const float4*)(kg + (size_t)sidx[w][row] * 64 + ln * 4);
            o.x = f2bf(v.x); o.y = f2bf(v.y); o.z = f2bf(v.z); o.w = f2bf(v.w);
        }
        *(ushort4*)&As[w][row * 72 + ln * 4] = o;
    }

    f32x4 acc[4][4];
    #pragma unroll
    for (int i = 0; i < 4; ++i)
        #pragma unroll
        for (int j = 0; j < 4; ++j)
            acc[i][j] = (f32x4){0.f, 0.f, 0.f, 0.f};

    #pragma unroll
    for (int s = 0; s < 2; ++s) {
        bf16x8 a[4], bb[4];
        #pragma unroll
        for (int mt = 0; mt < 4; ++mt)
            a[mt] = *(const bf16x8*)&As[w][(mt * 16 + ln) * 72 + s * 32 + quad * 8];
        #pragma unroll
        for (int nt = 0; nt < 4; ++nt)
            bb[nt] = *(const bf16x8*)&Ws[(nt * 16 + ln) * 72 + s * 32 + quad * 8];
        #pragma unroll
        for (int mt = 0; mt < 4; ++mt)
            #pragma unroll
            for (int nt = 0; nt < 4; ++nt)
                acc[mt][nt] = __builtin_amdgcn_mfma_f32_16x16x32_bf16(
                    a[mt], bb[nt], acc[mt][nt], 0, 0, 0);
    }

    // relu(c + bkg) for rows < cnt, column-sum over rows
    float bv[4];
    #pragma unroll
    for (int nt = 0; nt < 4; ++nt) bv[nt] = bkg[nt * 16 + ln];
    float cs[4] = {0.f, 0.f, 0.f, 0.f};
    #pragma unroll
    for (int mt = 0; mt < 4; ++mt) {
        #pragma unroll
        for (int i = 0; i < 4; ++i) {
            const int row = mt * 16 + quad * 4 + i;
            const float mk = (row < cnt) ? 1.f : 0.f;
            #pragma unroll
            for (int nt = 0; nt < 4; ++nt)
                cs[nt] += mk * fmaxf(acc[mt][nt][i] + bv[nt], 0.f);
        }
    }
    #pragma unroll
    for (int nt = 0; nt < 4; ++nt) {
        cs[nt] += __shfl_xor(cs[nt], 16, 64);
        cs[nt] += __shfl_xor(cs[nt], 32, 64);
    }
    if (quad == 0) {
        #pragma unroll
        for (int nt = 0; nt < 4; ++nt)
            know[(size_t)b * 64 + nt * 16 + ln] = f2bf(cs[nt]);
    }
}

// =================== fused MLP v2: 16 rows/block, 512 blocks ===================
// LDS: actA 16x520 (16.6K) + actB 16x136 (4.4K) + actC 16x72 (2.3K)
//      + Wbuf 2x128x72 (36.9K)  = ~59 KB -> 2 blocks/CU.
// Weights streamed in [NCH x 64] chunks, double-buffered with register prefetch.

template<int K, int N, int STRIN, int STROUT, bool RELU, bool ADD, bool OUT_F32>
__device__ __forceinline__ void layer(
    const ushort* actIn, ushort* actOut,
    const ushort* __restrict__ Wt, const float* __restrict__ bias,
    ushort* Wbuf, float* __restrict__ gOut, int m0, int t)
{
    constexpr int NCH    = (N < 128) ? N : 128;  // n-chunk rows
    constexpr int KC     = K / 64;               // k-chunks per n-chunk
    constexpr int CHUNKS = (N / NCH) * KC;
    constexpr int PASSES = NCH / 32;             // uint4 staging passes
    constexpr int NT     = NCH / 64;             // 16-col tiles per wave

    const int w = t >> 6, lane = t & 63, ln = lane & 15, quad = lane >> 4;

    uint4 pf[PASSES];
    // prefetch chunk 0
    #pragma unroll
    for (int p = 0; p < PASSES; ++p) {
        int gid = p * 256 + t, row = gid >> 3, seg = gid & 7;
        pf[p] = *(const uint4*)(Wt + (size_t)row * K + seg * 8);
    }

    f32x4 acc[NT];
    for (int c = 0; c < CHUNKS; ++c) {
        const int nc = c / KC, k0 = (c % KC) * 64;
        ushort* buf = Wbuf + (c & 1) * (128 * 72);

        __syncthreads();
        #pragma unroll
        for (int p = 0; p < PASSES; ++p) {
            int gid = p * 256 + t, row = gid >> 3, seg = gid & 7;
            *(uint4*)&buf[row * 72 + seg * 8] = pf[p];
        }
        if (c + 1 < CHUNKS) {
            const int c2 = c + 1, nc2 = c2 / KC, k02 = (c2 % KC) * 64;
            #pragma unroll
            for (int p = 0; p < PASSES; ++p) {
                int gid = p * 256 + t, row = gid >> 3, seg = gid & 7;
                pf[p] = *(const uint4*)(Wt + (size_t)(nc2 * NCH + row) * K + k02 + seg * 8);
            }
        }
        __syncthreads();

        if (c % KC == 0) {
            #pragma unroll
            for (int nt = 0; nt < NT; ++nt) acc[nt] = (f32x4){0.f, 0.f, 0.f, 0.f};
        }
        #pragma unroll
        for (int s = 0; s < 2; ++s) {
            bf16x8 a = *(const bf16x8*)&actIn[ln * STRIN + k0 + s * 32 + quad * 8];
            #pragma unroll
            for (int nt = 0; nt < NT; ++nt) {
                bf16x8 bfr = *(const bf16x8*)&buf[(w * (NCH / 4) + nt * 16 + ln) * 72 + s * 32 + quad * 8];
                acc[nt] = __builtin_amdgcn_mfma_f32_16x16x32_bf16(a, bfr, acc[nt], 0, 0, 0);
            }
        }
        if (c % KC == KC - 1) {
            #pragma unroll
            for (int nt = 0; nt < NT; ++nt) {
                const int col = nc * NCH + w * (NCH / 4) + nt * 16 + ln;
                const float bv = bias[col];
                #pragma unroll
                for (int i = 0; i < 4; ++i) {
                    const int row = quad * 4 + i;
                    float v = acc[nt][i] + bv;
                    if (RELU) v = fmaxf(v, 0.f);
                    if constexpr (ADD) v += bf2f(actOut[row * STROUT + col]);
                    if constexpr (OUT_F32)
                        gOut[(size_t)(m0 + row) * N + col] = v;
                    else
                        actOut[row * STROUT + col] = f2bf(v);
                }
            }
        }
    }
}

__global__ __launch_bounds__(256) void fused_mlp(
    const float* __restrict__ x, const ushort* __restrict__ know,
    const ushort* __restrict__ W1at, const float* __restrict__ b1a,
    const ushort* __restrict__ W1bt, const float* __restrict__ b1b,
    const ushort* __restrict__ W1ct, const float* __restrict__ b1c,
    const ushort* __restrict__ W1dt, const float* __restrict__ b1d,
    const ushort* __restrict__ W2t,  const float* __restrict__ b2,
    float* __restrict__ out)
{
    __shared__ ushort actA[16 * 520];
    __shared__ ushort actB[16 * 136];
    __shared__ ushort actC[16 * 72];
    __shared__ ushort Wbuf[2 * 128 * 72];

    const int t  = threadIdx.x;
    const int m0 = blockIdx.x * 16;

    // phase 0: stage x (fp32 -> bf16) and know tile
    #pragma unroll
    for (int p = 0; p < 8; ++p) {
        int gid = p * 256 + t;
        int row = gid >> 7, c4 = gid & 127;   // 128 float4 per row of 512
        float4 v = *(const float4*)(x + (size_t)(m0 + row) * 512 + c4 * 4);
        ushort4 o;
        o.x = f2bf(v.x); o.y = f2bf(v.y); o.z = f2bf(v.z); o.w = f2bf(v.w);
        *(ushort4*)&actA[row * 520 + c4 * 4] = o;
    }
    if (t < 128) {
        int row = t >> 3, seg = t & 7;
        *(uint4*)&actC[row * 72 + seg * 8] =
            *(const uint4*)(know + (size_t)(m0 + row) * 64 + seg * 8);
    }
    // (first layer's leading __syncthreads covers phase-0 visibility)

    layer<512, 128, 520, 136, true,  false, false>(actA, actB, W1at, b1a, Wbuf, nullptr, m0, t);
    layer<128, 512, 136, 520, true,  false, false>(actB, actA, W1bt, b1b, Wbuf, nullptr, m0, t);
    layer<512, 128, 520, 136, true,  false, false>(actA, actB, W1ct, b1c, Wbuf, nullptr, m0, t);
    layer<128, 64,  136, 72,  true,  true,  false>(actB, actC, W1dt, b1d, Wbuf, nullptr, m0, t);
    layer<64,  1024, 72, 0,   false, false, true >(actC, actC, W2t,  b2,  Wbuf, out,     m0, t);
}

extern "C" void kernel_launch(void* const* d_in, const int* in_sizes, int n_in,
                              void* d_out, int out_size, void* d_ws, size_t ws_size,
                              hipStream_t stream)
{
    const float* x    = (const float*)d_in[0];
    const float* kg   = (const float*)d_in[1];
    const int*   idx  = (const int*)d_in[2];
    const int*   mask = (const int*)d_in[3];
    const float* Wkg  = (const float*)d_in[4];
    const float* bkg  = (const float*)d_in[5];
    const float* W1a  = (const float*)d_in[6];
    const float* b1a  = (const float*)d_in[7];
    const float* W1b  = (const float*)d_in[8];
    const float* b1b  = (const float*)d_in[9];
    const float* W1c  = (const float*)d_in[10];
    const float* b1c  = (const float*)d_in[11];
    const float* W1d  = (const float*)d_in[12];
    const float* b1d  = (const float*)d_in[13];
    const float* W2   = (const float*)d_in[14];
    const float* b2   = (const float*)d_in[15];
    float* out = (float*)d_out;

    // ws (ushorts): know [8192][64] + transposed bf16 weights (~1.6 MB total)
    ushort* know = (ushort*)d_ws;                    // [8192][64]
    ushort* Wkgt = know + (size_t)BB * 64;           // [64][64]
    ushort* W1at = Wkgt + 64 * 64;                   // [128][512]
    ushort* W1bt = W1at + 512 * 128;                 // [512][128]
    ushort* W1ct = W1bt + 128 * 512;                 // [128][512]
    ushort* W1dt = W1ct + 512 * 128;                 // [64][128]
    ushort* W2t  = W1dt + 128 * 64;                  // [1024][64]

    prep_weights<<<(274432 + 255) / 256, 256, 0, stream>>>(
        Wkg, Wkgt, W1a, W1at, W1b, W1bt, W1c, W1ct, W1d, W1dt, W2, W2t);

    knowledge_bf16<<<BB / 4, 256, 0, stream>>>(kg, idx, mask, Wkgt, bkg, know);

    fused_mlp<<<BB / 16, 256, 0, stream>>>(
        x, know, W1at, b1a, W1bt, b1b, W1ct, b1c, W1dt, b1d, W2t, b2, out);
}

// Round 5
// 173.211 us; speedup vs baseline: 1.2908x; 1.2908x over previous
//
#include <hip/hip_runtime.h>

#define BB 8192
#define KCNT 50

typedef __attribute__((ext_vector_type(8))) short bf16x8;
typedef __attribute__((ext_vector_type(4))) float f32x4;

__device__ __forceinline__ ushort f2bf(float f) {
    union { float f; unsigned u; } v; v.f = f;
    unsigned r = v.u + 0x7FFFu + ((v.u >> 16) & 1u);
    return (ushort)(r >> 16);
}
__device__ __forceinline__ float bf2f(ushort h) {
    union { unsigned u; float f; } v; v.u = ((unsigned)h) << 16;
    return v.f;
}

// fragment-major index: frag f=(nt*KC+kc) holds a 16n x 32k block as
// 64 lanes x 16B, so ds_read_b128 at f*1024 + lane*16 is conflict-free.
__device__ __forceinline__ int fidx(int K, int n, int k) {
    int nt = n >> 4, ln = n & 15, kc = k >> 5, quad = (k >> 3) & 3, j = k & 7;
    return (((nt * (K >> 5) + kc) * 4 + quad) * 16 + ln) * 8 + j;
}

// ---- prep: all 6 weights [K][N] fp32 -> fragment-major bf16 ----
__global__ __launch_bounds__(256) void prep_weights(
    const float* __restrict__ s0, ushort* __restrict__ d0,   // Wkg 64x64
    const float* __restrict__ s1, ushort* __restrict__ d1,   // W1a 512x128
    const float* __restrict__ s2, ushort* __restrict__ d2,   // W1b 128x512
    const float* __restrict__ s3, ushort* __restrict__ d3,   // W1c 512x128
    const float* __restrict__ s4, ushort* __restrict__ d4,   // W1d 128x64
    const float* __restrict__ s5, ushort* __restrict__ d5)   // W2 64x1024
{
    int gid = blockIdx.x * 256 + threadIdx.x;
    const float* s; ushort* d; int K, N, base;
    if      (gid < 4096)   { s = s0; d = d0; K = 64;  N = 64;   base = 0; }
    else if (gid < 69632)  { s = s1; d = d1; K = 512; N = 128;  base = 4096; }
    else if (gid < 135168) { s = s2; d = d2; K = 128; N = 512;  base = 69632; }
    else if (gid < 200704) { s = s3; d = d3; K = 512; N = 128;  base = 135168; }
    else if (gid < 208896) { s = s4; d = d4; K = 128; N = 64;   base = 200704; }
    else if (gid < 274432) { s = s5; d = d5; K = 64;  N = 1024; base = 208896; }
    else return;
    int e = gid - base;          // e = k*N + n  (coalesced read)
    int k = e / N, n = e % N;
    d[fidx(K, n, k)] = f2bf(s[e]);
}

// =============== weight-stationary layer kernel ===============
// Full weights in LDS (fragment-major), staged once, ONE barrier.
// 256 blocks x 4 waves = 1024 tasks = 512 strips(16 rows) x 2 n-halves.
// A-fragments direct from global; no LDS for activations; no inner barriers.
template<int K, int N, int HALVES, bool A_F32, bool RELU, bool ADDK, bool OUTF32>
__global__ __launch_bounds__(256) void layer_ws(
    const void* __restrict__ Ain, const ushort* __restrict__ Wf,
    const float* __restrict__ bias, const ushort* __restrict__ knw,
    void* __restrict__ Cout)
{
    constexpr int KC   = K / 32;
    constexpr int NTH  = (N / 16) / HALVES;  // n-tiles per task
    __shared__ ushort Wl[N * K];

    const int t = threadIdx.x;
    constexpr int PASS = (N * K / 8) / 256;  // uint4 staging passes
    #pragma unroll
    for (int p = 0; p < PASS; ++p) {
        int i = p * 256 + t;
        ((uint4*)Wl)[i] = ((const uint4*)Wf)[i];
    }
    __syncthreads();

    const int w = t >> 6, lane = t & 63, ln = lane & 15, quad = lane >> 4;
    const int wid   = blockIdx.x * 4 + w;
    const int strip = wid / HALVES;
    const int half  = wid % HALVES;
    const int m0    = strip * 16;

    // A-fragments: row m0+ln, k = kc*32 + quad*8 .. +8
    bf16x8 a[KC];
    if constexpr (A_F32) {
        const float* A = (const float*)Ain;
        #pragma unroll
        for (int kc = 0; kc < KC; ++kc) {
            const float* p = A + (size_t)(m0 + ln) * K + kc * 32 + quad * 8;
            float4 u = *(const float4*)p;
            float4 v = *(const float4*)(p + 4);
            bf16x8 r;
            r[0] = (short)f2bf(u.x); r[1] = (short)f2bf(u.y);
            r[2] = (short)f2bf(u.z); r[3] = (short)f2bf(u.w);
            r[4] = (short)f2bf(v.x); r[5] = (short)f2bf(v.y);
            r[6] = (short)f2bf(v.z); r[7] = (short)f2bf(v.w);
            a[kc] = r;
        }
    } else {
        const ushort* A = (const ushort*)Ain;
        #pragma unroll
        for (int kc = 0; kc < KC; ++kc)
            a[kc] = *(const bf16x8*)(A + (size_t)(m0 + ln) * K + kc * 32 + quad * 8);
    }

    f32x4 acc[NTH];
    #pragma unroll
    for (int nt = 0; nt < NTH; ++nt) acc[nt] = (f32x4){0.f, 0.f, 0.f, 0.f};

    #pragma unroll
    for (int kc = 0; kc < KC; ++kc)
        #pragma unroll
        for (int nt = 0; nt < NTH; ++nt) {
            bf16x8 b = *(const bf16x8*)&Wl[(((half * NTH + nt) * KC) + kc) * 512 + lane * 8];
            acc[nt] = __builtin_amdgcn_mfma_f32_16x16x32_bf16(a[kc], b, acc[nt], 0, 0, 0);
        }

    // epilogue: C/D layout col=ln, row=quad*4+i
    #pragma unroll
    for (int nt = 0; nt < NTH; ++nt) {
        const int col = (half * NTH + nt) * 16 + ln;
        const float bv = bias[col];
        #pragma unroll
        for (int i = 0; i < 4; ++i) {
            const int row = m0 + quad * 4 + i;
            float v = acc[nt][i] + bv;
            if constexpr (RELU) v = fmaxf(v, 0.f);
            if constexpr (ADDK) v += bf2f(knw[(size_t)row * 64 + col]);
            if constexpr (OUTF32) ((float*)Cout)[(size_t)row * N + col] = v;
            else                  ((ushort*)Cout)[(size_t)row * N + col] = f2bf(v);
        }
    }
}

// ---- knowledge: compacted gather direct to A-registers, Wkg in 8KB LDS ----
// 1 wave per batch, 4 batches/block, ~9KB LDS -> ~8 blocks/CU resident.
__global__ __launch_bounds__(256) void knowledge_ws(
    const float* __restrict__ kg, const int* __restrict__ idx,
    const int* __restrict__ mask, const ushort* __restrict__ Wf,
    const float* __restrict__ bkg, ushort* __restrict__ know)
{
    __shared__ ushort Ws[64 * 64];   // fragment-major Wkg, 8 KB
    __shared__ int sidx[4][64];

    const int t = threadIdx.x;
    const int w = t >> 6, lane = t & 63, ln = lane & 15, quad = lane >> 4;
    const int b = blockIdx.x * 4 + w;

    #pragma unroll
    for (int p = 0; p < 2; ++p) {
        int i = p * 256 + t;
        ((uint4*)Ws)[i] = ((const uint4*)Wf)[i];
    }
    int cnt;
    {
        int id = 0, mk = 0;
        if (lane < KCNT) {
            id = idx[(size_t)b * KCNT + lane];
            mk = mask[(size_t)b * KCNT + lane];
        }
        unsigned long long bal = __ballot(mk != 0);
        cnt = __popcll(bal);
        if (mk) {
            int pos = __popcll(bal & ((1ull << lane) - 1ull));
            sidx[w][pos] = id;
        }
    }
    __syncthreads();

    // gather A-fragments straight to registers: a[mt][s]
    bf16x8 a[4][2];
    #pragma unroll
    for (int mt = 0; mt < 4; ++mt) {
        const int r = mt * 16 + ln;
        const bool val = r < cnt;
        #pragma unroll
        for (int s = 0; s < 2; ++s) {
            bf16x8 rr = (bf16x8){0, 0, 0, 0, 0, 0, 0, 0};
            if (val) {
                const float* p = kg + (size_t)sidx[w][r] * 64 + s * 32 + quad * 8;
                float4 u = *(const float4*)p;
                float4 v = *(const float4*)(p + 4);
                rr[0] = (short)f2bf(u.x); rr[1] = (short)f2bf(u.y);
                rr[2] = (short)f2bf(u.z); rr[3] = (short)f2bf(u.w);
                rr[4] = (short)f2bf(v.x); rr[5] = (short)f2bf(v.y);
                rr[6] = (short)f2bf(v.z); rr[7] = (short)f2bf(v.w);
            }
            a[mt][s] = rr;
        }
    }

    f32x4 acc[4][4];
    #pragma unroll
    for (int i = 0; i < 4; ++i)
        #pragma unroll
        for (int j = 0; j < 4; ++j)
            acc[i][j] = (f32x4){0.f, 0.f, 0.f, 0.f};

    #pragma unroll
    for (int s = 0; s < 2; ++s)
        #pragma unroll
        for (int nt = 0; nt < 4; ++nt) {
            bf16x8 bb = *(const bf16x8*)&Ws[((nt * 2 + s) * 64 + lane) * 8];
            #pragma unroll
            for (int mt = 0; mt < 4; ++mt)
                acc[mt][nt] = __builtin_amdgcn_mfma_f32_16x16x32_bf16(
                    a[mt][s], bb, acc[mt][nt], 0, 0, 0);
        }

    // relu(c + bkg) for rows < cnt, column-sum, wave reduce
    float bv[4];
    #pragma unroll
    for (int nt = 0; nt < 4; ++nt) bv[nt] = bkg[nt * 16 + ln];
    float cs[4] = {0.f, 0.f, 0.f, 0.f};
    #pragma unroll
    for (int mt = 0; mt < 4; ++mt)
        #pragma unroll
        for (int i = 0; i < 4; ++i) {
            const int row = mt * 16 + quad * 4 + i;
            const float mk = (row < cnt) ? 1.f : 0.f;
            #pragma unroll
            for (int nt = 0; nt < 4; ++nt)
                cs[nt] += mk * fmaxf(acc[mt][nt][i] + bv[nt], 0.f);
        }
    #pragma unroll
    for (int nt = 0; nt < 4; ++nt) {
        cs[nt] += __shfl_xor(cs[nt], 16, 64);
        cs[nt] += __shfl_xor(cs[nt], 32, 64);
    }
    if (quad == 0) {
        #pragma unroll
        for (int nt = 0; nt < 4; ++nt)
            know[(size_t)b * 64 + nt * 16 + ln] = f2bf(cs[nt]);
    }
}

extern "C" void kernel_launch(void* const* d_in, const int* in_sizes, int n_in,
                              void* d_out, int out_size, void* d_ws, size_t ws_size,
                              hipStream_t stream)
{
    const float* x    = (const float*)d_in[0];
    const float* kg   = (const float*)d_in[1];
    const int*   idx  = (const int*)d_in[2];
    const int*   mask = (const int*)d_in[3];
    const float* Wkg  = (const float*)d_in[4];
    const float* bkg  = (const float*)d_in[5];
    const float* W1a  = (const float*)d_in[6];
    const float* b1a  = (const float*)d_in[7];
    const float* W1b  = (const float*)d_in[8];
    const float* b1b  = (const float*)d_in[9];
    const float* W1c  = (const float*)d_in[10];
    const float* b1c  = (const float*)d_in[11];
    const float* W1d  = (const float*)d_in[12];
    const float* b1d  = (const float*)d_in[13];
    const float* W2   = (const float*)d_in[14];
    const float* b2   = (const float*)d_in[15];
    float* out = (float*)d_out;

    // ws (ushorts): know + frag-major weights + bf16 activations (~16 MB)
    ushort* know = (ushort*)d_ws;                    // [8192][64]
    ushort* Wkgt = know + (size_t)BB * 64;           // 64*64
    ushort* W1at = Wkgt + 64 * 64;                   // 512*128
    ushort* W1bt = W1at + 512 * 128;                 // 128*512
    ushort* W1ct = W1bt + 128 * 512;                 // 512*128
    ushort* W1dt = W1ct + 512 * 128;                 // 128*64
    ushort* W2t  = W1dt + 128 * 64;                  // 64*1024
    ushort* h1   = W2t  + 64 * 1024;                 // [8192][128]
    ushort* h2   = h1   + (size_t)BB * 128;          // [8192][512]
    ushort* h3   = h2   + (size_t)BB * 512;          // [8192][128]
    ushort* h4s  = h3   + (size_t)BB * 128;          // [8192][64]  (relu(h4)+know)

    prep_weights<<<(274432 + 255) / 256, 256, 0, stream>>>(
        Wkg, Wkgt, W1a, W1at, W1b, W1bt, W1c, W1ct, W1d, W1dt, W2, W2t);

    knowledge_ws<<<BB / 4, 256, 0, stream>>>(kg, idx, mask, Wkgt, bkg, know);

    layer_ws<512, 128, 2, true,  true,  false, false><<<256, 256, 0, stream>>>(x,   W1at, b1a, nullptr, h1);
    layer_ws<128, 512, 2, false, true,  false, false><<<256, 256, 0, stream>>>(h1,  W1bt, b1b, nullptr, h2);
    layer_ws<512, 128, 2, false, true,  false, false><<<256, 256, 0, stream>>>(h2,  W1ct, b1c, nullptr, h3);
    layer_ws<128, 64,  2, false, true,  true,  false><<<256, 256, 0, stream>>>(h3,  W1dt, b1d, know,    h4s);
    layer_ws<64, 1024, 2, false, false, false, true ><<<256, 256, 0, stream>>>(h4s, W2t,  b2,  nullptr, out);
}

// Round 6
// 164.074 us; speedup vs baseline: 1.3627x; 1.0557x over previous
//
#include <hip/hip_runtime.h>

#define BB 8192
#define KCNT 50

typedef __attribute__((ext_vector_type(8))) short bf16x8;
typedef __attribute__((ext_vector_type(4))) float f32x4;

__device__ __forceinline__ ushort f2bf(float f) {
    union { float f; unsigned u; } v; v.f = f;
    unsigned r = v.u + 0x7FFFu + ((v.u >> 16) & 1u);
    return (ushort)(r >> 16);
}
__device__ __forceinline__ float bf2f(ushort h) {
    union { unsigned u; float f; } v; v.u = ((unsigned)h) << 16;
    return v.f;
}

// fragment-major index: frag f=(nt*KC+kc) holds a 16n x 32k block as
// 64 lanes x 16B, so reads at f*1024B + lane*16B are perfectly coalesced.
__device__ __forceinline__ int fidx(int K, int n, int k) {
    int nt = n >> 4, ln = n & 15, kc = k >> 5, quad = (k >> 3) & 3, j = k & 7;
    return (((nt * (K >> 5) + kc) * 4 + quad) * 16 + ln) * 8 + j;
}

// ---- prep: all 6 weights [K][N] fp32 -> fragment-major bf16 ----
__global__ __launch_bounds__(256) void prep_weights(
    const float* __restrict__ s0, ushort* __restrict__ d0,   // Wkg 64x64
    const float* __restrict__ s1, ushort* __restrict__ d1,   // W1a 512x128
    const float* __restrict__ s2, ushort* __restrict__ d2,   // W1b 128x512
    const float* __restrict__ s3, ushort* __restrict__ d3,   // W1c 512x128
    const float* __restrict__ s4, ushort* __restrict__ d4,   // W1d 128x64
    const float* __restrict__ s5, ushort* __restrict__ d5)   // W2 64x1024
{
    int gid = blockIdx.x * 256 + threadIdx.x;
    const float* s; ushort* d; int K, N, base;
    if      (gid < 4096)   { s = s0; d = d0; K = 64;  N = 64;   base = 0; }
    else if (gid < 69632)  { s = s1; d = d1; K = 512; N = 128;  base = 4096; }
    else if (gid < 135168) { s = s2; d = d2; K = 128; N = 512;  base = 69632; }
    else if (gid < 200704) { s = s3; d = d3; K = 512; N = 128;  base = 135168; }
    else if (gid < 208896) { s = s4; d = d4; K = 128; N = 64;   base = 200704; }
    else if (gid < 274432) { s = s5; d = d5; K = 64;  N = 1024; base = 208896; }
    else return;
    int e = gid - base;          // e = k*N + n  (coalesced read)
    int k = e / N, n = e % N;
    d[fidx(K, n, k)] = f2bf(s[e]);
}

// ---- knowledge: compacted gather direct to A-registers, Wkg in 8KB LDS ----
__global__ __launch_bounds__(256) void knowledge_ws(
    const float* __restrict__ kg, const int* __restrict__ idx,
    const int* __restrict__ mask, const ushort* __restrict__ Wf,
    const float* __restrict__ bkg, ushort* __restrict__ know)
{
    __shared__ ushort Ws[64 * 64];   // fragment-major Wkg, 8 KB
    __shared__ int sidx[4][64];

    const int t = threadIdx.x;
    const int w = t >> 6, lane = t & 63, ln = lane & 15, quad = lane >> 4;
    const int b = blockIdx.x * 4 + w;

    #pragma unroll
    for (int p = 0; p < 2; ++p) {
        int i = p * 256 + t;
        ((uint4*)Ws)[i] = ((const uint4*)Wf)[i];
    }
    int cnt;
    {
        int id = 0, mk = 0;
        if (lane < KCNT) {
            id = idx[(size_t)b * KCNT + lane];
            mk = mask[(size_t)b * KCNT + lane];
        }
        unsigned long long bal = __ballot(mk != 0);
        cnt = __popcll(bal);
        if (mk) {
            int pos = __popcll(bal & ((1ull << lane) - 1ull));
            sidx[w][pos] = id;
        }
    }
    __syncthreads();

    bf16x8 a[4][2];
    #pragma unroll
    for (int mt = 0; mt < 4; ++mt) {
        const int r = mt * 16 + ln;
        const bool val = r < cnt;
        #pragma unroll
        for (int s = 0; s < 2; ++s) {
            bf16x8 rr = (bf16x8){0, 0, 0, 0, 0, 0, 0, 0};
            if (val) {
                const float* p = kg + (size_t)sidx[w][r] * 64 + s * 32 + quad * 8;
                float4 u = *(const float4*)p;
                float4 v = *(const float4*)(p + 4);
                rr[0] = (short)f2bf(u.x); rr[1] = (short)f2bf(u.y);
                rr[2] = (short)f2bf(u.z); rr[3] = (short)f2bf(u.w);
                rr[4] = (short)f2bf(v.x); rr[5] = (short)f2bf(v.y);
                rr[6] = (short)f2bf(v.z); rr[7] = (short)f2bf(v.w);
            }
            a[mt][s] = rr;
        }
    }

    f32x4 acc[4][4];
    #pragma unroll
    for (int i = 0; i < 4; ++i)
        #pragma unroll
        for (int j = 0; j < 4; ++j)
            acc[i][j] = (f32x4){0.f, 0.f, 0.f, 0.f};

    #pragma unroll
    for (int s = 0; s < 2; ++s)
        #pragma unroll
        for (int nt = 0; nt < 4; ++nt) {
            bf16x8 bb = *(const bf16x8*)&Ws[((nt * 2 + s) * 64 + lane) * 8];
            #pragma unroll
            for (int mt = 0; mt < 4; ++mt)
                acc[mt][nt] = __builtin_amdgcn_mfma_f32_16x16x32_bf16(
                    a[mt][s], bb, acc[mt][nt], 0, 0, 0);
        }

    float bv[4];
    #pragma unroll
    for (int nt = 0; nt < 4; ++nt) bv[nt] = bkg[nt * 16 + ln];
    float cs[4] = {0.f, 0.f, 0.f, 0.f};
    #pragma unroll
    for (int mt = 0; mt < 4; ++mt)
        #pragma unroll
        for (int i = 0; i < 4; ++i) {
            const int row = mt * 16 + quad * 4 + i;
            const float mk = (row < cnt) ? 1.f : 0.f;
            #pragma unroll
            for (int nt = 0; nt < 4; ++nt)
                cs[nt] += mk * fmaxf(acc[mt][nt][i] + bv[nt], 0.f);
        }
    #pragma unroll
    for (int nt = 0; nt < 4; ++nt) {
        cs[nt] += __shfl_xor(cs[nt], 16, 64);
        cs[nt] += __shfl_xor(cs[nt], 32, 64);
    }
    if (quad == 0) {
        #pragma unroll
        for (int nt = 0; nt < 4; ++nt)
            know[(size_t)b * 64 + nt * 16 + ln] = f2bf(cs[nt]);
    }
}

// =============== fused whole-MLP kernel ===============
// 512 blocks x 16 rows. 4 waves own N/4 cols of every layer. Activations in
// LDS (C-layout write -> A-layout read). B-frags straight from L2-resident
// frag-major weights (16B/lane coalesced). One barrier per layer boundary.

template<int K, int N, int STRIN, int STROUT, bool AGLOBAL, bool RELU, bool ADDK, bool OUTGLOBAL>
__device__ __forceinline__ void wave_layer(
    const ushort* ldsIn, const float* __restrict__ gA, ushort* ldsOut,
    const ushort* __restrict__ Wf, const float* __restrict__ bias,
    const ushort* __restrict__ know, float* __restrict__ gOut,
    int m0, int lane, int w)
{
    constexpr int KC  = K / 32;
    constexpr int NTH = N / 64;       // n-tiles per wave
    const int ln = lane & 15, quad = lane >> 4;

    bf16x8 a[KC];
    if constexpr (AGLOBAL) {
        #pragma unroll
        for (int kc = 0; kc < KC; ++kc) {
            const float* p = gA + (size_t)(m0 + ln) * K + kc * 32 + quad * 8;
            float4 u = *(const float4*)p;
            float4 v = *(const float4*)(p + 4);
            bf16x8 r;
            r[0] = (short)f2bf(u.x); r[1] = (short)f2bf(u.y);
            r[2] = (short)f2bf(u.z); r[3] = (short)f2bf(u.w);
            r[4] = (short)f2bf(v.x); r[5] = (short)f2bf(v.y);
            r[6] = (short)f2bf(v.z); r[7] = (short)f2bf(v.w);
            a[kc] = r;
        }
    } else {
        #pragma unroll
        for (int kc = 0; kc < KC; ++kc)
            a[kc] = *(const bf16x8*)&ldsIn[ln * STRIN + kc * 32 + quad * 8];
    }

    f32x4 acc[NTH];
    #pragma unroll
    for (int nt = 0; nt < NTH; ++nt) acc[nt] = (f32x4){0.f, 0.f, 0.f, 0.f};

    #pragma unroll
    for (int kc = 0; kc < KC; ++kc)
        #pragma unroll
        for (int nt = 0; nt < NTH; ++nt) {
            bf16x8 b = *(const bf16x8*)(Wf + ((size_t)((w * NTH + nt) * KC + kc) * 64 + lane) * 8);
            acc[nt] = __builtin_amdgcn_mfma_f32_16x16x32_bf16(a[kc], b, acc[nt], 0, 0, 0);
        }

    #pragma unroll
    for (int nt = 0; nt < NTH; ++nt) {
        const int col = (w * NTH + nt) * 16 + ln;
        const float bv = bias[col];
        #pragma unroll
        for (int i = 0; i < 4; ++i) {
            const int row = quad * 4 + i;
            float v = acc[nt][i] + bv;
            if constexpr (RELU) v = fmaxf(v, 0.f);
            if constexpr (ADDK) v += bf2f(know[(size_t)(m0 + row) * 64 + col]);
            if constexpr (OUTGLOBAL) gOut[(size_t)(m0 + row) * N + col] = v;
            else                     ldsOut[row * STROUT + col] = f2bf(v);
        }
    }
}

__global__ __launch_bounds__(256, 2) void mlp_all(
    const float* __restrict__ x, const ushort* __restrict__ know,
    const ushort* __restrict__ W1at, const float* __restrict__ b1a,
    const ushort* __restrict__ W1bt, const float* __restrict__ b1b,
    const ushort* __restrict__ W1ct, const float* __restrict__ b1c,
    const ushort* __restrict__ W1dt, const float* __restrict__ b1d,
    const ushort* __restrict__ W2t,  const float* __restrict__ b2,
    float* __restrict__ out)
{
    __shared__ ushort bufA[16 * 520];   // h2
    __shared__ ushort bufB[16 * 136];   // h1 / h3
    __shared__ ushort bufC[16 * 72];    // relu(h4)+know

    const int t = threadIdx.x;
    const int w = t >> 6, lane = t & 63;
    const int m0 = blockIdx.x * 16;

    // L1: h1 = relu(x @ W1a + b1a)            512 -> 128 (A from global fp32)
    wave_layer<512, 128, 0, 136, true, true, false, false>(
        nullptr, x, bufB, W1at, b1a, nullptr, nullptr, m0, lane, w);
    __syncthreads();
    // L2: h2 = relu(h1 @ W1b + b1b)           128 -> 512
    wave_layer<128, 512, 136, 520, false, true, false, false>(
        bufB, nullptr, bufA, W1bt, b1b, nullptr, nullptr, m0, lane, w);
    __syncthreads();
    // L3: h3 = relu(h2 @ W1c + b1c)           512 -> 128
    wave_layer<512, 128, 520, 136, false, true, false, false>(
        bufA, nullptr, bufB, W1ct, b1c, nullptr, nullptr, m0, lane, w);
    __syncthreads();
    // L4: c = relu(h3 @ W1d + b1d) + know     128 -> 64
    wave_layer<128, 64, 136, 72, false, true, true, false>(
        bufB, nullptr, bufC, W1dt, b1d, know, nullptr, m0, lane, w);
    __syncthreads();
    // L5: out = c @ W2 + b2 (fp32 to global)  64 -> 1024
    wave_layer<64, 1024, 72, 0, false, false, false, true>(
        bufC, nullptr, nullptr, W2t, b2, nullptr, out, m0, lane, w);
}

extern "C" void kernel_launch(void* const* d_in, const int* in_sizes, int n_in,
                              void* d_out, int out_size, void* d_ws, size_t ws_size,
                              hipStream_t stream)
{
    const float* x    = (const float*)d_in[0];
    const float* kg   = (const float*)d_in[1];
    const int*   idx  = (const int*)d_in[2];
    const int*   mask = (const int*)d_in[3];
    const float* Wkg  = (const float*)d_in[4];
    const float* bkg  = (const float*)d_in[5];
    const float* W1a  = (const float*)d_in[6];
    const float* b1a  = (const float*)d_in[7];
    const float* W1b  = (const float*)d_in[8];
    const float* b1b  = (const float*)d_in[9];
    const float* W1c  = (const float*)d_in[10];
    const float* b1c  = (const float*)d_in[11];
    const float* W1d  = (const float*)d_in[12];
    const float* b1d  = (const float*)d_in[13];
    const float* W2   = (const float*)d_in[14];
    const float* b2   = (const float*)d_in[15];
    float* out = (float*)d_out;

    // ws (ushorts): know [8192][64] + frag-major bf16 weights (~1.6 MB)
    ushort* know = (ushort*)d_ws;                    // [8192][64]
    ushort* Wkgt = know + (size_t)BB * 64;           // 64*64
    ushort* W1at = Wkgt + 64 * 64;                   // 512*128
    ushort* W1bt = W1at + 512 * 128;                 // 128*512
    ushort* W1ct = W1bt + 128 * 512;                 // 512*128
    ushort* W1dt = W1ct + 512 * 128;                 // 128*64
    ushort* W2t  = W1dt + 128 * 64;                  // 64*1024

    prep_weights<<<(274432 + 255) / 256, 256, 0, stream>>>(
        Wkg, Wkgt, W1a, W1at, W1b, W1bt, W1c, W1ct, W1d, W1dt, W2, W2t);

    knowledge_ws<<<BB / 4, 256, 0, stream>>>(kg, idx, mask, Wkgt, bkg, know);

    mlp_all<<<BB / 16, 256, 0, stream>>>(
        x, know, W1at, b1a, W1bt, b1b, W1ct, b1c, W1dt, b1d, W2t, b2, out);
}

// Round 7
// 158.329 us; speedup vs baseline: 1.4122x; 1.0363x over previous
//
#include <hip/hip_runtime.h>

#define BB 8192
#define KCNT 50

typedef __attribute__((ext_vector_type(8))) short bf16x8;
typedef __attribute__((ext_vector_type(4))) float f32x4;

__device__ __forceinline__ ushort f2bf(float f) {
    union { float f; unsigned u; } v; v.f = f;
    unsigned r = v.u + 0x7FFFu + ((v.u >> 16) & 1u);
    return (ushort)(r >> 16);
}
__device__ __forceinline__ float bf2f(ushort h) {
    union { unsigned u; float f; } v; v.u = ((unsigned)h) << 16;
    return v.f;
}

// fragment-major index: frag f=(nt*KC+kc) holds a 16n x 32k block as
// 64 lanes x 16B, so reads at f*1024B + lane*16B are perfectly coalesced.
__device__ __forceinline__ int fidx(int K, int n, int k) {
    int nt = n >> 4, ln = n & 15, kc = k >> 5, quad = (k >> 3) & 3, j = k & 7;
    return (((nt * (K >> 5) + kc) * 4 + quad) * 16 + ln) * 8 + j;
}

// ---- prep: all 6 weights [K][N] fp32 -> fragment-major bf16 ----
__global__ __launch_bounds__(256) void prep_weights(
    const float* __restrict__ s0, ushort* __restrict__ d0,   // Wkg 64x64
    const float* __restrict__ s1, ushort* __restrict__ d1,   // W1a 512x128
    const float* __restrict__ s2, ushort* __restrict__ d2,   // W1b 128x512
    const float* __restrict__ s3, ushort* __restrict__ d3,   // W1c 512x128
    const float* __restrict__ s4, ushort* __restrict__ d4,   // W1d 128x64
    const float* __restrict__ s5, ushort* __restrict__ d5)   // W2 64x1024
{
    int gid = blockIdx.x * 256 + threadIdx.x;
    const float* s; ushort* d; int K, N, base;
    if      (gid < 4096)   { s = s0; d = d0; K = 64;  N = 64;   base = 0; }
    else if (gid < 69632)  { s = s1; d = d1; K = 512; N = 128;  base = 4096; }
    else if (gid < 135168) { s = s2; d = d2; K = 128; N = 512;  base = 69632; }
    else if (gid < 200704) { s = s3; d = d3; K = 512; N = 128;  base = 135168; }
    else if (gid < 208896) { s = s4; d = d4; K = 128; N = 64;   base = 200704; }
    else if (gid < 274432) { s = s5; d = d5; K = 64;  N = 1024; base = 208896; }
    else return;
    int e = gid - base;          // e = k*N + n  (coalesced read)
    int k = e / N, n = e % N;
    d[fidx(K, n, k)] = f2bf(s[e]);
}

// ---- per-wave layer: A from LDS (or global fp32), B-frags from global
// frag-major weights (L2-hot, 16B/lane coalesced), C to LDS (or global).
template<int K, int N, int STRIN, int STROUT, bool AGLOBAL, bool RELU, bool ADDK, bool OUTGLOBAL>
__device__ __forceinline__ void wave_layer(
    const ushort* ldsIn, const float* __restrict__ gA, ushort* ldsOut,
    const ushort* __restrict__ Wf, const float* __restrict__ bias,
    const ushort* knowL, float* __restrict__ gOut,
    int m0, int lane, int w)
{
    constexpr int KC  = K / 32;
    constexpr int NTH = N / 64;       // n-tiles per wave
    const int ln = lane & 15, quad = lane >> 4;

    bf16x8 a[KC];
    if constexpr (AGLOBAL) {
        #pragma unroll
        for (int kc = 0; kc < KC; ++kc) {
            const float* p = gA + (size_t)(m0 + ln) * K + kc * 32 + quad * 8;
            float4 u = *(const float4*)p;
            float4 v = *(const float4*)(p + 4);
            bf16x8 r;
            r[0] = (short)f2bf(u.x); r[1] = (short)f2bf(u.y);
            r[2] = (short)f2bf(u.z); r[3] = (short)f2bf(u.w);
            r[4] = (short)f2bf(v.x); r[5] = (short)f2bf(v.y);
            r[6] = (short)f2bf(v.z); r[7] = (short)f2bf(v.w);
            a[kc] = r;
        }
    } else {
        #pragma unroll
        for (int kc = 0; kc < KC; ++kc)
            a[kc] = *(const bf16x8*)&ldsIn[ln * STRIN + kc * 32 + quad * 8];
    }

    f32x4 acc[NTH];
    #pragma unroll
    for (int nt = 0; nt < NTH; ++nt) acc[nt] = (f32x4){0.f, 0.f, 0.f, 0.f};

    #pragma unroll
    for (int kc = 0; kc < KC; ++kc)
        #pragma unroll
        for (int nt = 0; nt < NTH; ++nt) {
            bf16x8 b = *(const bf16x8*)(Wf + ((size_t)((w * NTH + nt) * KC + kc) * 64 + lane) * 8);
            acc[nt] = __builtin_amdgcn_mfma_f32_16x16x32_bf16(a[kc], b, acc[nt], 0, 0, 0);
        }

    #pragma unroll
    for (int nt = 0; nt < NTH; ++nt) {
        const int col = (w * NTH + nt) * 16 + ln;
        const float bv = bias[col];
        #pragma unroll
        for (int i = 0; i < 4; ++i) {
            const int row = quad * 4 + i;
            float v = acc[nt][i] + bv;
            if constexpr (RELU) v = fmaxf(v, 0.f);
            if constexpr (ADDK) v += bf2f(knowL[row * 72 + col]);
            if constexpr (OUTGLOBAL) gOut[(size_t)(m0 + row) * N + col] = v;
            else                     ldsOut[row * STROUT + col] = f2bf(v);
        }
    }
}

// =============== megakernel: knowledge + whole MLP, 512 blocks x 16 rows ===============
__global__ __launch_bounds__(256, 2) void mega(
    const float* __restrict__ x, const float* __restrict__ kg,
    const int* __restrict__ idx, const int* __restrict__ mask,
    const ushort* __restrict__ Wkgf, const float* __restrict__ bkg,
    const ushort* __restrict__ W1at, const float* __restrict__ b1a,
    const ushort* __restrict__ W1bt, const float* __restrict__ b1b,
    const ushort* __restrict__ W1ct, const float* __restrict__ b1c,
    const ushort* __restrict__ W1dt, const float* __restrict__ b1d,
    const ushort* __restrict__ W2t,  const float* __restrict__ b2,
    float* __restrict__ out)
{
    __shared__ ushort bufA[16 * 520];   // h2
    __shared__ ushort bufB[16 * 136];   // h1 / h3
    __shared__ ushort bufC[16 * 72];    // relu(h4)+know
    __shared__ ushort knowL[16 * 72];   // knowledge, local rows
    __shared__ int    sidxL[4][64];     // per-wave compacted indices (reused per sub)

    const int t = threadIdx.x;
    const int w = t >> 6, lane = t & 63, ln = lane & 15, quad = lane >> 4;
    const int m0 = blockIdx.x * 16;

    // ---------- knowledge: wave w handles batches m0 + w*4 .. +3 ----------
    // Wkg B-frags hoisted to registers (8 x 16B/lane, L2-hot)
    bf16x8 wb[4][2];
    #pragma unroll
    for (int nt = 0; nt < 4; ++nt)
        #pragma unroll
        for (int s = 0; s < 2; ++s)
            wb[nt][s] = *(const bf16x8*)(Wkgf + ((size_t)((nt * 2 + s) * 64 + lane)) * 8);

    // preload idx/mask for all 4 sub-batches (coalesced, lanes 0..49)
    int ids[4], mks[4];
    #pragma unroll
    for (int sub = 0; sub < 4; ++sub) {
        const int b = m0 + w * 4 + sub;
        ids[sub] = 0; mks[sub] = 0;
        if (lane < KCNT) {
            ids[sub] = idx[(size_t)b * KCNT + lane];
            mks[sub] = mask[(size_t)b * KCNT + lane];
        }
    }

    #pragma unroll 1
    for (int sub = 0; sub < 4; ++sub) {
        unsigned long long bal = __ballot(mks[sub] != 0);
        const int cnt = __popcll(bal);
        if (mks[sub]) {
            int pos = __popcll(bal & ((1ull << lane) - 1ull));
            sidxL[w][pos] = ids[sub];
        }
        // wave-local LDS RAW: in-wave DS ordering + compiler lgkmcnt handles it.

        // compacted gather direct to A-registers
        bf16x8 a[4][2];
        #pragma unroll
        for (int mt = 0; mt < 4; ++mt) {
            const int r = mt * 16 + ln;
            const bool val = r < cnt;
            #pragma unroll
            for (int s = 0; s < 2; ++s) {
                bf16x8 rr = (bf16x8){0, 0, 0, 0, 0, 0, 0, 0};
                if (val) {
                    const float* p = kg + (size_t)sidxL[w][r] * 64 + s * 32 + quad * 8;
                    float4 u = *(const float4*)p;
                    float4 v = *(const float4*)(p + 4);
                    rr[0] = (short)f2bf(u.x); rr[1] = (short)f2bf(u.y);
                    rr[2] = (short)f2bf(u.z); rr[3] = (short)f2bf(u.w);
                    rr[4] = (short)f2bf(v.x); rr[5] = (short)f2bf(v.y);
                    rr[6] = (short)f2bf(v.z); rr[7] = (short)f2bf(v.w);
                }
                a[mt][s] = rr;
            }
        }

        f32x4 acc[4][4];
        #pragma unroll
        for (int i = 0; i < 4; ++i)
            #pragma unroll
            for (int j = 0; j < 4; ++j)
                acc[i][j] = (f32x4){0.f, 0.f, 0.f, 0.f};

        #pragma unroll
        for (int s = 0; s < 2; ++s)
            #pragma unroll
            for (int nt = 0; nt < 4; ++nt)
                #pragma unroll
                for (int mt = 0; mt < 4; ++mt)
                    acc[mt][nt] = __builtin_amdgcn_mfma_f32_16x16x32_bf16(
                        a[mt][s], wb[nt][s], acc[mt][nt], 0, 0, 0);

        // relu(c + bkg) for rows < cnt, column-sum, wave reduce
        float cs[4] = {0.f, 0.f, 0.f, 0.f};
        #pragma unroll
        for (int mt = 0; mt < 4; ++mt)
            #pragma unroll
            for (int i = 0; i < 4; ++i) {
                const int row = mt * 16 + quad * 4 + i;
                const float mk = (row < cnt) ? 1.f : 0.f;
                #pragma unroll
                for (int nt = 0; nt < 4; ++nt)
                    cs[nt] += mk * fmaxf(acc[mt][nt][i] + bkg[nt * 16 + ln], 0.f);
            }
        #pragma unroll
        for (int nt = 0; nt < 4; ++nt) {
            cs[nt] += __shfl_xor(cs[nt], 16, 64);
            cs[nt] += __shfl_xor(cs[nt], 32, 64);
        }
        if (quad == 0) {
            #pragma unroll
            for (int nt = 0; nt < 4; ++nt)
                knowL[(w * 4 + sub) * 72 + nt * 16 + ln] = f2bf(cs[nt]);
        }
    }

    // ---------- MLP chain (knowL made visible by the L1/L2/L3 barriers) ----------
    // L1: h1 = relu(x @ W1a + b1a)            512 -> 128 (A from global fp32)
    wave_layer<512, 128, 0, 136, true, true, false, false>(
        nullptr, x, bufB, W1at, b1a, nullptr, nullptr, m0, lane, w);
    __syncthreads();
    // L2: h2 = relu(h1 @ W1b + b1b)           128 -> 512
    wave_layer<128, 512, 136, 520, false, true, false, false>(
        bufB, nullptr, bufA, W1bt, b1b, nullptr, nullptr, m0, lane, w);
    __syncthreads();
    // L3: h3 = relu(h2 @ W1c + b1c)           512 -> 128
    wave_layer<512, 128, 520, 136, false, true, false, false>(
        bufA, nullptr, bufB, W1ct, b1c, nullptr, nullptr, m0, lane, w);
    __syncthreads();
    // L4: c = relu(h3 @ W1d + b1d) + knowledge   128 -> 64
    wave_layer<128, 64, 136, 72, false, true, true, false>(
        bufB, nullptr, bufC, W1dt, b1d, knowL, nullptr, m0, lane, w);
    __syncthreads();
    // L5: out = c @ W2 + b2 (fp32 to global)  64 -> 1024
    wave_layer<64, 1024, 72, 0, false, false, false, true>(
        bufC, nullptr, nullptr, W2t, b2, nullptr, out, m0, lane, w);
}

extern "C" void kernel_launch(void* const* d_in, const int* in_sizes, int n_in,
                              void* d_out, int out_size, void* d_ws, size_t ws_size,
                              hipStream_t stream)
{
    const float* x    = (const float*)d_in[0];
    const float* kg   = (const float*)d_in[1];
    const int*   idx  = (const int*)d_in[2];
    const int*   mask = (const int*)d_in[3];
    const float* Wkg  = (const float*)d_in[4];
    const float* bkg  = (const float*)d_in[5];
    const float* W1a  = (const float*)d_in[6];
    const float* b1a  = (const float*)d_in[7];
    const float* W1b  = (const float*)d_in[8];
    const float* b1b  = (const float*)d_in[9];
    const float* W1c  = (const float*)d_in[10];
    const float* b1c  = (const float*)d_in[11];
    const float* W1d  = (const float*)d_in[12];
    const float* b1d  = (const float*)d_in[13];
    const float* W2   = (const float*)d_in[14];
    const float* b2   = (const float*)d_in[15];
    float* out = (float*)d_out;

    // ws (ushorts): frag-major bf16 weights only (~540 KB)
    ushort* Wkgt = (ushort*)d_ws;                    // 64*64
    ushort* W1at = Wkgt + 64 * 64;                   // 512*128
    ushort* W1bt = W1at + 512 * 128;                 // 128*512
    ushort* W1ct = W1bt + 128 * 512;                 // 512*128
    ushort* W1dt = W1ct + 512 * 128;                 // 128*64
    ushort* W2t  = W1dt + 128 * 64;                  // 64*1024

    prep_weights<<<(274432 + 255) / 256, 256, 0, stream>>>(
        Wkg, Wkgt, W1a, W1at, W1b, W1bt, W1c, W1ct, W1d, W1dt, W2, W2t);

    mega<<<BB / 16, 256, 0, stream>>>(
        x, kg, idx, mask, Wkgt, bkg,
        W1at, b1a, W1bt, b1b, W1ct, b1c, W1dt, b1d, W2t, b2, out);
}